// Round 11
// baseline (591.863 us; speedup 1.0000x reference)
//
#include <hip/hip_runtime.h>
#include <hip/hip_bf16.h>
#include <math.h>

#define DIM 1024
#define NEXP 64
#define NN 65
#define DG 256
#define T_TOK 2048
#define THR_EDGE 0.5f

typedef __attribute__((ext_vector_type(8))) short bf16x8;
typedef __attribute__((ext_vector_type(4))) float f32x4;
typedef unsigned short ushort_t;
typedef __attribute__((ext_vector_type(8))) unsigned short us8;

// RNE float->bf16 (raw ushort) and back
static __device__ __forceinline__ ushort_t f2bf(float x) {
  unsigned u = __float_as_uint(x);
  unsigned r = (u + 0x7FFFu + ((u >> 16) & 1u)) >> 16;
  return (ushort_t)r;
}
static __device__ __forceinline__ float bf2f(ushort_t h) {
  return __uint_as_float(((unsigned)h) << 16);
}

// ---------------- setup kernels ----------------

// K-split expT partials: part[kc][i][j] = sum_{k in chunk} Xp[k][i]*mlp[k][j]
__global__ __launch_bounds__(256) void k_expT_ks(const float* __restrict__ Xp,
                                                 const float* __restrict__ mlp,
                                                 float* __restrict__ part) {
  int i0 = blockIdx.y * 4;
  int j = blockIdx.x * 256 + threadIdx.x;
  int k0 = blockIdx.z * 128;
  float acc0 = 0.f, acc1 = 0.f, acc2 = 0.f, acc3 = 0.f;
#pragma unroll 4
  for (int k = k0; k < k0 + 128; ++k) {
    float m = mlp[(size_t)k * DIM + j];            // coalesced
    const float* xr = &Xp[(size_t)k * NEXP + i0];  // uniform -> s_load
    acc0 = fmaf(xr[0], m, acc0);
    acc1 = fmaf(xr[1], m, acc1);
    acc2 = fmaf(xr[2], m, acc2);
    acc3 = fmaf(xr[3], m, acc3);
  }
  size_t base = ((size_t)blockIdx.z * NEXP + i0) * DIM + j;
  part[base + 0 * DIM] = acc0;
  part[base + 1 * DIM] = acc1;
  part[base + 2 * DIM] = acc2;
  part[base + 3 * DIM] = acc3;
}

// reduce partials: expT[i][j] = relu(sum_kc part), also expTT[j][i]
__global__ __launch_bounds__(256) void k_expT_red(const float* __restrict__ part,
                                                  float* __restrict__ expT,
                                                  float* __restrict__ expTT) {
  int e = blockIdx.x * 256 + threadIdx.x;   // 64K elems
  int i = e >> 10, j = e & 1023;
  float v = 0.f;
#pragma unroll
  for (int kc = 0; kc < 8; ++kc)
    v += part[(size_t)kc * (NEXP * DIM) + e];
  v = fmaxf(v, 0.f);
  expT[e] = v;
  expTT[(size_t)j * NEXP + i] = v;
}

// W01 = W0@W1, emitted directly as frag-major bf16 hi/lo (B-operand, K=1024,N=256)
__global__ __launch_bounds__(256) void k_W01(const float* __restrict__ W0,
                                             const float* __restrict__ W1,
                                             ushort_t* __restrict__ Bh,
                                             ushort_t* __restrict__ Bl) {
  int i = blockIdx.x;      // k-dim (1024)
  int d = threadIdx.x;     // n-dim (256)
  float acc = 0.f;
#pragma unroll 4
  for (int k = 0; k < DG; ++k)
    acc = fmaf(W0[i * DG + k], W1[k * DG + d], acc);
  int dt = d >> 4, c = d & 15, ks = i >> 5, kg = (i >> 3) & 3, j = i & 7;
  size_t idx = (((size_t)dt * 32 + ks) * 64 + kg * 16 + c) * 8 + j;
  ushort_t h = f2bf(acc);
  Bh[idx] = h;
  Bl[idx] = f2bf(acc - bf2f(h));
}

// w3p[i] = dot(W3 row i, pw) — one block per i
__global__ __launch_bounds__(256) void k_w3p(const float* __restrict__ W3,
                                             const float* __restrict__ pw,
                                             float* __restrict__ w3p) {
  __shared__ float red[4];
  int i = blockIdx.x;
  int tid = threadIdx.x, lane = tid & 63, w = tid >> 6;
  const float* r = &W3[(size_t)i * DIM];
  float s = r[tid] * pw[tid]
          + r[tid + 256] * pw[tid + 256]
          + r[tid + 512] * pw[tid + 512]
          + r[tid + 768] * pw[tid + 768];
#pragma unroll
  for (int off = 32; off > 0; off >>= 1)
    s += __shfl_down(s, off, 64);
  if (lane == 0) red[w] = s;
  __syncthreads();
  if (tid == 0) w3p[i] = red[0] + red[1] + red[2] + red[3];
}

// split x into bf16 hi/lo row-major planes (A-operand)
__global__ __launch_bounds__(256) void k_splitX(const float* __restrict__ X,
                                                ushort_t* __restrict__ Xh,
                                                ushort_t* __restrict__ Xl) {
  size_t base = ((size_t)blockIdx.x * 256 + threadIdx.x) * 8;
  us8 h, l;
#pragma unroll
  for (int u = 0; u < 8; ++u) {
    float v = X[base + u];
    ushort_t hh = f2bf(v);
    h[u] = hh;
    l[u] = f2bf(v - bf2f(hh));
  }
  *(us8*)(Xh + base) = h;
  *(us8*)(Xl + base) = l;
}

// split B [K][N] fp32 into frag-major bf16 hi/lo. thread = (k0 8-aligned, n)
__global__ __launch_bounds__(256) void k_splitB(const float* __restrict__ B,
                                                ushort_t* __restrict__ Bh,
                                                ushort_t* __restrict__ Bl,
                                                int K, int N) {
  int k0 = blockIdx.x * 8;
  int d = blockIdx.y * 256 + threadIdx.x;
  int KS = K >> 5;
  int dt = d >> 4, c = d & 15, ks = k0 >> 5, kg = (k0 >> 3) & 3;
  size_t idx = (((size_t)dt * KS + ks) * 64 + kg * 16 + c) * 8;
  us8 h, l;
#pragma unroll
  for (int j = 0; j < 8; ++j) {
    float v = B[(size_t)(k0 + j) * N + d];
    ushort_t hh = f2bf(v);
    h[j] = hh;
    l[j] = f2bf(v - bf2f(hh));
  }
  *(us8*)(Bh + idx) = h;
  *(us8*)(Bl + idx) = l;
}

// D[i][j] = dot(exp_i, exp_j); 4-way k-split per block + LDS reduce
__global__ __launch_bounds__(256) void k_cos(const float* __restrict__ expTT,
                                             float* __restrict__ D) {
  __shared__ float part[4][NEXP];
  int i = blockIdx.x;
  int tid = threadIdx.x;
  int j = tid & 63, qd = tid >> 6;
  float acc = 0.f;
  int d0 = qd * 256;
  for (int d = d0; d < d0 + 256; ++d) {
    float ei = expTT[(size_t)d * NEXP + i];
    float ej = expTT[(size_t)d * NEXP + j];
    acc = fmaf(ei, ej, acc);
  }
  part[qd][j] = acc;
  __syncthreads();
  if (tid < NEXP)
    D[i * NEXP + tid] = part[0][tid] + part[1][tid] + part[2][tid] + part[3][tid];
}

// Split W2 into bf16 hi/lo planes in MFMA-frag-major layout (K=256 -> KS=8)
__global__ __launch_bounds__(256) void k_splitW2(const float* __restrict__ W2,
                                                 ushort_t* __restrict__ Wh,
                                                 ushort_t* __restrict__ Wl) {
  int k = blockIdx.x;
  int d = threadIdx.x;
  float w = W2[(size_t)k * DG + d];
  ushort_t h = f2bf(w);
  ushort_t l = f2bf(w - bf2f(h));
  int dt = d >> 4, c = d & 15, ks = k >> 5, kg = (k >> 3) & 3, j = k & 7;
  int idx = (((dt * 8 + ks) * 64) + kg * 16 + c) * 8 + j;
  Wh[idx] = h;
  Wl[idx] = l;
}

// Build normalized adjacency Ahat [65][65] and q = Ahat @ a0
__global__ __launch_bounds__(256) void k_buildA(const float* __restrict__ D,
                                                float* __restrict__ Ahat,
                                                float* __restrict__ q) {
  __shared__ float nrm[NEXP];
  __shared__ float Ar[NN][NN];
  __shared__ float Al[NN][NN];
  __shared__ float dd[NN];
  __shared__ float a0[NN];
  int tid = threadIdx.x;
  if (tid < NEXP) nrm[tid] = fmaxf(sqrtf(D[tid * NEXP + tid]), 1e-8f);
  __syncthreads();
  for (int e = tid; e < NN * NN; e += 256) {
    int n = e / NN, m = e - n * NN;
    float v = 0.f;
    if (n == m) v = 1.f;                              // self loop
    else if (m == NEXP) v = (n < NEXP) ? 1.f : 0.f;   // token -> each expert
    else if (n < NEXP && m < n) {                     // edge m->n for m<n
      float c = D[m * NEXP + n] / (nrm[m] * nrm[n]);
      v = (c > THR_EDGE) ? 1.f : 0.f;
    }
    Ar[n][m] = v;
  }
  __syncthreads();
  if (tid < NN) {
    float s = 0.f;
    for (int m = 0; m < NN; ++m) s += Ar[tid][m];
    dd[tid] = 1.0f / sqrtf(s);
  }
  __syncthreads();
  for (int e = tid; e < NN * NN; e += 256) {
    int n = e / NN, m = e - n * NN;
    float v = Ar[n][m] * dd[n] * dd[m];
    Al[n][m] = v;
    Ahat[e] = v;
  }
  __syncthreads();
  if (tid < NN) a0[tid] = Al[tid][NEXP];
  __syncthreads();
  if (tid < NN) {
    float s = 0.f;
    for (int m = 0; m < NN; ++m) s = fmaf(Al[tid][m], a0[m], s);
    q[tid] = s;
  }
}

// expW[m][d] = sum_k expT[m][k] * W0[k][d]
__global__ __launch_bounds__(256) void k_expW(const float* __restrict__ expT,
                                              const float* __restrict__ W0,
                                              float* __restrict__ expW) {
  int m = blockIdx.x, d = threadIdx.x;
  float acc = 0.f;
#pragma unroll 4
  for (int k = 0; k < DIM; ++k)
    acc = fmaf(expT[m * DIM + k], W0[k * DG + d], acc);
  expW[m * DG + d] = acc;
}

// CW1[n][d] = ((Ahat[:, :64] @ expW) @ W1)[n][d]
__global__ __launch_bounds__(256) void k_CW1(const float* __restrict__ Ahat,
                                             const float* __restrict__ expW,
                                             const float* __restrict__ W1,
                                             float* __restrict__ CW1) {
  __shared__ float c0[DG];
  int n = blockIdx.x, d = threadIdx.x;
  float acc = 0.f;
  for (int m = 0; m < NEXP; ++m)
    acc = fmaf(Ahat[n * NN + m], expW[m * DG + d], acc);
  c0[d] = acc;
  __syncthreads();
  float b = 0.f;
#pragma unroll 4
  for (int k = 0; k < DG; ++k)
    b = fmaf(c0[k], W1[k * DG + d], b);
  CW1[n * DG + d] = b;
}

// P[n][d] = (Ahat @ CW1)[n][d]
__global__ __launch_bounds__(256) void k_P(const float* __restrict__ Ahat,
                                           const float* __restrict__ CW1,
                                           float* __restrict__ P) {
  int n = blockIdx.x, d = threadIdx.x;
  float acc = 0.f;
  for (int m = 0; m < NN; ++m)
    acc = fmaf(Ahat[n * NN + m], CW1[m * DG + d], acc);
  P[n * DG + d] = acc;
}

// ---------------- k_mgemm v2: MFMA split-bf16 GEMM C = [relu](A@B) ----------------
template <int NT, bool RELU, bool OSPLIT>
__global__ __launch_bounds__(256) void k_mgemm(const ushort_t* __restrict__ Ah,
                                               const ushort_t* __restrict__ Al,
                                               const ushort_t* __restrict__ Bh,
                                               const ushort_t* __restrict__ Bl,
                                               float* __restrict__ C,
                                               ushort_t* __restrict__ Ch,
                                               ushort_t* __restrict__ Cl,
                                               int M, int N, int K) {
  int tid = threadIdx.x, lane = tid & 63, w = tid >> 6;
  int t0 = blockIdx.x * 64 + w * 16;
  int n0 = blockIdx.y * (NT * 16);
  int row = lane & 15, kg = lane >> 4;
  int KS = K >> 5;

  f32x4 acc[NT];
#pragma unroll
  for (int nt = 0; nt < NT; ++nt) acc[nt] = (f32x4){0.f, 0.f, 0.f, 0.f};

  const ushort_t* pA0 = Ah + (size_t)(t0 + row) * K + kg * 8;
  const ushort_t* pA1 = Al + (size_t)(t0 + row) * K + kg * 8;

  for (int kc = 0; kc < KS; kc += 8) {   // K-chunk of 256
    bf16x8 ah[8], al[8];
#pragma unroll
    for (int ks = 0; ks < 8; ++ks) {
      ah[ks] = *(const bf16x8*)(pA0 + (kc + ks) * 32);
      al[ks] = *(const bf16x8*)(pA1 + (kc + ks) * 32);
    }
#pragma unroll
    for (int nt = 0; nt < NT; ++nt) {
      int dt = (n0 >> 4) + nt;
      const ushort_t* pBh = Bh + ((size_t)dt * KS + kc) * 512 + lane * 8;
      const ushort_t* pBl = Bl + ((size_t)dt * KS + kc) * 512 + lane * 8;
      bf16x8 bh[8], bl[8];
#pragma unroll
      for (int ks = 0; ks < 8; ++ks) {
        bh[ks] = *(const bf16x8*)(pBh + ks * 512);
        bl[ks] = *(const bf16x8*)(pBl + ks * 512);
      }
#pragma unroll
      for (int ks = 0; ks < 8; ++ks) {
        acc[nt] = __builtin_amdgcn_mfma_f32_16x16x32_bf16(ah[ks], bh[ks], acc[nt], 0, 0, 0);
        acc[nt] = __builtin_amdgcn_mfma_f32_16x16x32_bf16(al[ks], bh[ks], acc[nt], 0, 0, 0);
        acc[nt] = __builtin_amdgcn_mfma_f32_16x16x32_bf16(ah[ks], bl[ks], acc[nt], 0, 0, 0);
        acc[nt] = __builtin_amdgcn_mfma_f32_16x16x32_bf16(al[ks], bl[ks], acc[nt], 0, 0, 0);
      }
    }
  }

#pragma unroll
  for (int nt = 0; nt < NT; ++nt) {
    int cc = n0 + nt * 16 + row;
#pragma unroll
    for (int r = 0; r < 4; ++r) {
      float v = acc[nt][r];
      if (RELU) v = fmaxf(v, 0.f);
      size_t o = (size_t)(t0 + kg * 4 + r) * N + cc;
      if (OSPLIT) {
        ushort_t h = f2bf(v);
        Ch[o] = h;
        Cl[o] = f2bf(v - bf2f(h));
      } else {
        C[o] = v;
      }
    }
  }
}

// ---------------- k_mix: G[nn][t][k] = sum_m Ahat[n0+nn][m]*relu(P[m][k]+q[m]V[t][k]) ----
// v2: 4-way independent accumulators (the 65-deep dependent fmaf chain was
// latency-bound at ~260 cyc/nn; split -> issue-bound).
__global__ __launch_bounds__(256) void k_mix(const float* __restrict__ V,
                                             const float* __restrict__ P,
                                             const float* __restrict__ Ahat,
                                             const float* __restrict__ q,
                                             ushort_t* __restrict__ Gh,
                                             ushort_t* __restrict__ Gl,
                                             int n0, int nch) {
  int t = blockIdx.x;
  int k = threadIdx.x;
  float v = V[(size_t)t * DG + k];
  float r[NN];
#pragma unroll
  for (int m = 0; m < NN; ++m)
    r[m] = fmaxf(fmaf(q[m], v, P[m * DG + k]), 0.f);
  for (int nn = 0; nn < nch; ++nn) {
    const float* arow = &Ahat[(size_t)(n0 + nn) * NN];  // uniform -> s_loads
    float a0 = 0.f, a1 = 0.f, a2 = 0.f, a3 = 0.f;
#pragma unroll
    for (int m = 0; m < 16; ++m) {
      a0 = fmaf(arow[m +  0], r[m +  0], a0);
      a1 = fmaf(arow[m + 16], r[m + 16], a1);
      a2 = fmaf(arow[m + 32], r[m + 32], a2);
      a3 = fmaf(arow[m + 48], r[m + 48], a3);
    }
    float acc = ((a0 + a1) + (a2 + a3)) + arow[64] * r[64];
    size_t idx = ((size_t)nn * T_TOK + t) * DG + k;
    ushort_t h = f2bf(acc);
    Gh[idx] = h;
    Gl[idx] = f2bf(acc - bf2f(h));
  }
}

// ---------------- k_zgemm v2 (MFMA split-bf16) ----------------
// Round-10 PMC: MfmaUtil 15.7%, dur 83us — B-frag loads were issued per-ks,
// dependent, 256 L2-latency stalls/wave. Fix (proven on k_mgemm): batch all 16
// B-frags per dt before the 32-MFMA chain; wp preload moved to epilogue.
__global__ __launch_bounds__(256, 2) void k_zgemm(const ushort_t* __restrict__ Gh,
                                                  const ushort_t* __restrict__ Gl,
                                                  const ushort_t* __restrict__ Wh,
                                                  const ushort_t* __restrict__ Wl,
                                                  const float* __restrict__ w3p,
                                                  float* __restrict__ s2T,
                                                  int n0) {
  int tid = threadIdx.x, lane = tid & 63, w = tid >> 6;
  int ny = blockIdx.y;
  int t0 = blockIdx.x * 64 + w * 16;
  int row = lane & 15, kg = lane >> 4;

  const ushort_t* Ah = Gh + ((size_t)ny * T_TOK + t0 + row) * DG + kg * 8;
  const ushort_t* Al = Gl + ((size_t)ny * T_TOK + t0 + row) * DG + kg * 8;
  bf16x8 ah[8], al[8];
#pragma unroll
  for (int ks = 0; ks < 8; ++ks) {
    ah[ks] = *(const bf16x8*)(Ah + ks * 32);
    al[ks] = *(const bf16x8*)(Al + ks * 32);
  }

  f32x4 acc[16];
#pragma unroll
  for (int dt = 0; dt < 16; ++dt) acc[dt] = (f32x4){0.f, 0.f, 0.f, 0.f};

#pragma unroll
  for (int dt = 0; dt < 16; ++dt) {
    const ushort_t* Bh = Wh + (size_t)dt * 4096 + lane * 8;
    const ushort_t* Bl = Wl + (size_t)dt * 4096 + lane * 8;
    // batch all 16 B-frag loads (independent) before the MFMA chain
    bf16x8 bh[8], bl[8];
#pragma unroll
    for (int ks = 0; ks < 8; ++ks) {
      bh[ks] = *(const bf16x8*)(Bh + ks * 512);
      bl[ks] = *(const bf16x8*)(Bl + ks * 512);
    }
#pragma unroll
    for (int ks = 0; ks < 8; ++ks) {
      acc[dt] = __builtin_amdgcn_mfma_f32_16x16x32_bf16(ah[ks], bh[ks], acc[dt], 0, 0, 0);
      acc[dt] = __builtin_amdgcn_mfma_f32_16x16x32_bf16(al[ks], bh[ks], acc[dt], 0, 0, 0);
      acc[dt] = __builtin_amdgcn_mfma_f32_16x16x32_bf16(ah[ks], bl[ks], acc[dt], 0, 0, 0);
      acc[dt] = __builtin_amdgcn_mfma_f32_16x16x32_bf16(al[ks], bl[ks], acc[dt], 0, 0, 0);
    }
  }

  // epilogue: relu -> *w3p -> 16-lane reduce; wp loaded here (shorter live range)
  float v0 = 0.f, v1 = 0.f, v2 = 0.f, v3 = 0.f;
#pragma unroll
  for (int dt = 0; dt < 16; ++dt) {
    float wpd = w3p[dt * 16 + row];
    v0 = fmaf(fmaxf(acc[dt][0], 0.f), wpd, v0);
    v1 = fmaf(fmaxf(acc[dt][1], 0.f), wpd, v1);
    v2 = fmaf(fmaxf(acc[dt][2], 0.f), wpd, v2);
    v3 = fmaf(fmaxf(acc[dt][3], 0.f), wpd, v3);
  }
#pragma unroll
  for (int off = 1; off < 16; off <<= 1) {
    v0 += __shfl_xor(v0, off, 64);
    v1 += __shfl_xor(v1, off, 64);
    v2 += __shfl_xor(v2, off, 64);
    v3 += __shfl_xor(v3, off, 64);
  }
  if (row == 0) {
    int t = t0 + kg * 4;
    int n = n0 + ny;
    s2T[(size_t)(t + 0) * NN + n] = v0;
    s2T[(size_t)(t + 1) * NN + n] = v1;
    s2T[(size_t)(t + 2) * NN + n] = v2;
    s2T[(size_t)(t + 3) * NN + n] = v3;
  }
}

// ---------------- final: scores[t][j] = sum_m Ahat[j][m]*s2T[t][m]; softmax ----------------
__global__ __launch_bounds__(64) void k_final(const float* __restrict__ s2T,
                                              const float* __restrict__ Ahat,
                                              float* __restrict__ out) {
  __shared__ float s2l[NN];
  int t = blockIdx.x;
  int j = threadIdx.x;
  s2l[j] = s2T[(size_t)t * NN + j];
  if (j == 0) s2l[NEXP] = s2T[(size_t)t * NN + NEXP];
  __syncthreads();
  float sc = 0.f;
  for (int m = 0; m < NN; ++m)
    sc = fmaf(Ahat[j * NN + m], s2l[m], sc);
  float mx = sc;
#pragma unroll
  for (int off = 32; off > 0; off >>= 1)
    mx = fmaxf(mx, __shfl_xor(mx, off, 64));
  float e = expf(sc - mx);
  float sum = e;
#pragma unroll
  for (int off = 32; off > 0; off >>= 1)
    sum += __shfl_xor(sum, off, 64);
  out[(size_t)t * NEXP + j] = e / sum;
}

// ---------------- launch ----------------
extern "C" void kernel_launch(void* const* d_in, const int* in_sizes, int n_in,
                              void* d_out, int out_size, void* d_ws, size_t ws_size,
                              hipStream_t stream) {
  (void)in_sizes; (void)n_in; (void)out_size; (void)ws_size;
  const float* x   = (const float*)d_in[0];
  const float* Xp  = (const float*)d_in[1];
  const float* mlp = (const float*)d_in[2];
  const float* W0  = (const float*)d_in[3];
  const float* W1  = (const float*)d_in[4];
  const float* W2  = (const float*)d_in[5];
  const float* W3  = (const float*)d_in[6];
  const float* pw  = (const float*)d_in[7];
  float* out = (float*)d_out;
  float* ws = (float*)d_ws;

  // workspace layout (floats), total 18,934,752 fl ~= 75.7 MB — same as round 10
  float* expT  = ws + 0;         // 65536
  float* expTT = ws + 65536;     // 65536 (dead after k_cos -> W2f overlay)
  float* w3p   = ws + 131072;    // 256
  float* D     = ws + 131328;    // 4096
  float* Ahat  = ws + 135424;    // 4240
  float* q     = ws + 139664;    // 80
  float* expW  = ws + 139744;    // 16384
  float* CW1   = ws + 156128;    // 16640
  float* P     = ws + 172768;    // 16640
  float* s2T   = ws + 189408;    // 133120
  float* V     = ws + 322528;    // 524288
  float* part  = ws + 846816;    // 524288 (expT K-split partials; dead early)
  ushort_t* W01f_h = (ushort_t*)(ws + 1371104);  // 131072 fl
  ushort_t* W01f_l = (ushort_t*)(ws + 1502176);  // 131072 fl
  // big arena at 1633248: split planes (dead before k_mix) overlaid by Gc
  float* arena = ws + 1633248;
  ushort_t* Xh    = (ushort_t*)(arena);                 // 1048576 fl
  ushort_t* Xl    = (ushort_t*)(arena + 1048576);       // 1048576 fl
  ushort_t* mlpf_h = (ushort_t*)(arena + 2097152);      // 524288 fl
  ushort_t* mlpf_l = (ushort_t*)(arena + 2621440);      // 524288 fl
  ushort_t* XTh   = (ushort_t*)(arena + 3145728);       // 1048576 fl
  ushort_t* XTl   = (ushort_t*)(arena + 4194304);       // 1048576 fl
  ushort_t* Gc_h  = (ushort_t*)(arena);                 // 8650752 fl (overlays splits)
  ushort_t* Gc_l  = (ushort_t*)(arena + 8650752);       // 8650752 fl
  ushort_t* W2f_h = (ushort_t*)(ws + 65536);            // 32768 fl (overlay expTT)
  ushort_t* W2f_l = (ushort_t*)(ws + 65536 + 32768);    // 32768 fl

  // expert MLP (K-split, fp32 for the cos-threshold path)
  k_expT_ks<<<dim3(4, 16, 8), dim3(256), 0, stream>>>(Xp, mlp, part);
  k_expT_red<<<dim3(256), dim3(256), 0, stream>>>(part, expT, expTT);
  // independent setup
  k_W01<<<dim3(1024), dim3(256), 0, stream>>>(W0, W1, W01f_h, W01f_l);
  k_w3p<<<dim3(256), dim3(256), 0, stream>>>(W3, pw, w3p);
  k_splitX<<<dim3(1024), dim3(256), 0, stream>>>(x, Xh, Xl);
  k_splitB<<<dim3(128, 4), dim3(256), 0, stream>>>(mlp, mlpf_h, mlpf_l, DIM, DIM);
  // graph build
  k_cos<<<dim3(64), dim3(256), 0, stream>>>(expTT, D);
  k_splitW2<<<dim3(256), dim3(256), 0, stream>>>(W2, W2f_h, W2f_l);  // after k_cos
  k_buildA<<<dim3(1), dim3(256), 0, stream>>>(D, Ahat, q);
  k_expW<<<dim3(64), dim3(256), 0, stream>>>(expT, W0, expW);
  k_CW1<<<dim3(65), dim3(256), 0, stream>>>(Ahat, expW, W1, CW1);
  k_P<<<dim3(65), dim3(256), 0, stream>>>(Ahat, CW1, P);
  // XT = relu(x@mlp) as bf16 hi/lo (MFMA, NT=4 -> 512 blocks = 2/CU)
  k_mgemm<4, true, true><<<dim3(32, 16), dim3(256), 0, stream>>>(
      Xh, Xl, mlpf_h, mlpf_l, nullptr, XTh, XTl, T_TOK, DIM, DIM);
  // V = XT@W01 fp32 (MFMA, NT=2 -> 256 blocks)
  k_mgemm<2, false, false><<<dim3(32, 8), dim3(256), 0, stream>>>(
      XTh, XTl, W01f_h, W01f_l, V, nullptr, nullptr, T_TOK, DG, DIM);
  // chunked: G (bf16 hi/lo) = Ahat-mix; s2 = reduce(relu(G@W2)*w3p) via MFMA
  k_mix<<<dim3(T_TOK), dim3(256), 0, stream>>>(V, P, Ahat, q, Gc_h, Gc_l, 0, 33);
  k_zgemm<<<dim3(32, 33), dim3(256), 0, stream>>>(Gc_h, Gc_l, W2f_h, W2f_l, w3p, s2T, 0);
  k_mix<<<dim3(T_TOK), dim3(256), 0, stream>>>(V, P, Ahat, q, Gc_h, Gc_l, 33, 32);
  k_zgemm<<<dim3(32, 32), dim3(256), 0, stream>>>(Gc_h, Gc_l, W2f_h, W2f_l, w3p, s2T, 33);
  // scores + softmax -> out [2048,64]
  k_final<<<dim3(T_TOK), dim3(64), 0, stream>>>(s2T, Ahat, out);
}

// Round 12
// 545.037 us; speedup vs baseline: 1.0859x; 1.0859x over previous
//
#include <hip/hip_runtime.h>
#include <hip/hip_bf16.h>
#include <math.h>

#define DIM 1024
#define NEXP 64
#define NN 65
#define DG 256
#define T_TOK 2048
#define THR_EDGE 0.5f

typedef __attribute__((ext_vector_type(8))) short bf16x8;
typedef __attribute__((ext_vector_type(4))) float f32x4;
typedef unsigned short ushort_t;
typedef __attribute__((ext_vector_type(8))) unsigned short us8;

// RNE float->bf16 (raw ushort) and back
static __device__ __forceinline__ ushort_t f2bf(float x) {
  unsigned u = __float_as_uint(x);
  unsigned r = (u + 0x7FFFu + ((u >> 16) & 1u)) >> 16;
  return (ushort_t)r;
}
static __device__ __forceinline__ float bf2f(ushort_t h) {
  return __uint_as_float(((unsigned)h) << 16);
}

// ---------------- setup kernels ----------------

// K-split expT partials: part[kc][i][j] = sum_{k in chunk} Xp[k][i]*mlp[k][j]
__global__ __launch_bounds__(256) void k_expT_ks(const float* __restrict__ Xp,
                                                 const float* __restrict__ mlp,
                                                 float* __restrict__ part) {
  int i0 = blockIdx.y * 4;
  int j = blockIdx.x * 256 + threadIdx.x;
  int k0 = blockIdx.z * 128;
  float acc0 = 0.f, acc1 = 0.f, acc2 = 0.f, acc3 = 0.f;
#pragma unroll 4
  for (int k = k0; k < k0 + 128; ++k) {
    float m = mlp[(size_t)k * DIM + j];            // coalesced
    const float* xr = &Xp[(size_t)k * NEXP + i0];  // uniform -> s_load
    acc0 = fmaf(xr[0], m, acc0);
    acc1 = fmaf(xr[1], m, acc1);
    acc2 = fmaf(xr[2], m, acc2);
    acc3 = fmaf(xr[3], m, acc3);
  }
  size_t base = ((size_t)blockIdx.z * NEXP + i0) * DIM + j;
  part[base + 0 * DIM] = acc0;
  part[base + 1 * DIM] = acc1;
  part[base + 2 * DIM] = acc2;
  part[base + 3 * DIM] = acc3;
}

// reduce partials: expT[i][j] = relu(sum_kc part), also expTT[j][i]
__global__ __launch_bounds__(256) void k_expT_red(const float* __restrict__ part,
                                                  float* __restrict__ expT,
                                                  float* __restrict__ expTT) {
  int e = blockIdx.x * 256 + threadIdx.x;   // 64K elems
  int i = e >> 10, j = e & 1023;
  float v = 0.f;
#pragma unroll
  for (int kc = 0; kc < 8; ++kc)
    v += part[(size_t)kc * (NEXP * DIM) + e];
  v = fmaxf(v, 0.f);
  expT[e] = v;
  expTT[(size_t)j * NEXP + i] = v;
}

// W01 = W0@W1, emitted directly as frag-major bf16 hi/lo (B-operand, K=1024,N=256)
__global__ __launch_bounds__(256) void k_W01(const float* __restrict__ W0,
                                             const float* __restrict__ W1,
                                             ushort_t* __restrict__ Bh,
                                             ushort_t* __restrict__ Bl) {
  int i = blockIdx.x;      // k-dim (1024)
  int d = threadIdx.x;     // n-dim (256)
  float acc = 0.f;
#pragma unroll 4
  for (int k = 0; k < DG; ++k)
    acc = fmaf(W0[i * DG + k], W1[k * DG + d], acc);
  int dt = d >> 4, c = d & 15, ks = i >> 5, kg = (i >> 3) & 3, j = i & 7;
  size_t idx = (((size_t)dt * 32 + ks) * 64 + kg * 16 + c) * 8 + j;
  ushort_t h = f2bf(acc);
  Bh[idx] = h;
  Bl[idx] = f2bf(acc - bf2f(h));
}

// w3p[i] = dot(W3 row i, pw) — one block per i
__global__ __launch_bounds__(256) void k_w3p(const float* __restrict__ W3,
                                             const float* __restrict__ pw,
                                             float* __restrict__ w3p) {
  __shared__ float red[4];
  int i = blockIdx.x;
  int tid = threadIdx.x, lane = tid & 63, w = tid >> 6;
  const float* r = &W3[(size_t)i * DIM];
  float s = r[tid] * pw[tid]
          + r[tid + 256] * pw[tid + 256]
          + r[tid + 512] * pw[tid + 512]
          + r[tid + 768] * pw[tid + 768];
#pragma unroll
  for (int off = 32; off > 0; off >>= 1)
    s += __shfl_down(s, off, 64);
  if (lane == 0) red[w] = s;
  __syncthreads();
  if (tid == 0) w3p[i] = red[0] + red[1] + red[2] + red[3];
}

// split x into bf16 hi/lo row-major planes (A-operand)
__global__ __launch_bounds__(256) void k_splitX(const float* __restrict__ X,
                                                ushort_t* __restrict__ Xh,
                                                ushort_t* __restrict__ Xl) {
  size_t base = ((size_t)blockIdx.x * 256 + threadIdx.x) * 8;
  us8 h, l;
#pragma unroll
  for (int u = 0; u < 8; ++u) {
    float v = X[base + u];
    ushort_t hh = f2bf(v);
    h[u] = hh;
    l[u] = f2bf(v - bf2f(hh));
  }
  *(us8*)(Xh + base) = h;
  *(us8*)(Xl + base) = l;
}

// split B [K][N] fp32 into frag-major bf16 hi/lo. thread = (k0 8-aligned, n)
__global__ __launch_bounds__(256) void k_splitB(const float* __restrict__ B,
                                                ushort_t* __restrict__ Bh,
                                                ushort_t* __restrict__ Bl,
                                                int K, int N) {
  int k0 = blockIdx.x * 8;
  int d = blockIdx.y * 256 + threadIdx.x;
  int KS = K >> 5;
  int dt = d >> 4, c = d & 15, ks = k0 >> 5, kg = (k0 >> 3) & 3;
  size_t idx = (((size_t)dt * KS + ks) * 64 + kg * 16 + c) * 8;
  us8 h, l;
#pragma unroll
  for (int j = 0; j < 8; ++j) {
    float v = B[(size_t)(k0 + j) * N + d];
    ushort_t hh = f2bf(v);
    h[j] = hh;
    l[j] = f2bf(v - bf2f(hh));
  }
  *(us8*)(Bh + idx) = h;
  *(us8*)(Bl + idx) = l;
}

// D[i][j] = dot(exp_i, exp_j); 4-way k-split per block + LDS reduce
__global__ __launch_bounds__(256) void k_cos(const float* __restrict__ expTT,
                                             float* __restrict__ D) {
  __shared__ float part[4][NEXP];
  int i = blockIdx.x;
  int tid = threadIdx.x;
  int j = tid & 63, qd = tid >> 6;
  float acc = 0.f;
  int d0 = qd * 256;
  for (int d = d0; d < d0 + 256; ++d) {
    float ei = expTT[(size_t)d * NEXP + i];
    float ej = expTT[(size_t)d * NEXP + j];
    acc = fmaf(ei, ej, acc);
  }
  part[qd][j] = acc;
  __syncthreads();
  if (tid < NEXP)
    D[i * NEXP + tid] = part[0][tid] + part[1][tid] + part[2][tid] + part[3][tid];
}

// Split W2 into bf16 hi/lo planes in MFMA-frag-major layout (K=256 -> KS=8)
__global__ __launch_bounds__(256) void k_splitW2(const float* __restrict__ W2,
                                                 ushort_t* __restrict__ Wh,
                                                 ushort_t* __restrict__ Wl) {
  int k = blockIdx.x;
  int d = threadIdx.x;
  float w = W2[(size_t)k * DG + d];
  ushort_t h = f2bf(w);
  ushort_t l = f2bf(w - bf2f(h));
  int dt = d >> 4, c = d & 15, ks = k >> 5, kg = (k >> 3) & 3, j = k & 7;
  int idx = (((dt * 8 + ks) * 64) + kg * 16 + c) * 8 + j;
  Wh[idx] = h;
  Wl[idx] = l;
}

// Build normalized adjacency Ahat [65][65] and q = Ahat @ a0
__global__ __launch_bounds__(256) void k_buildA(const float* __restrict__ D,
                                                float* __restrict__ Ahat,
                                                float* __restrict__ q) {
  __shared__ float nrm[NEXP];
  __shared__ float Ar[NN][NN];
  __shared__ float Al[NN][NN];
  __shared__ float dd[NN];
  __shared__ float a0[NN];
  int tid = threadIdx.x;
  if (tid < NEXP) nrm[tid] = fmaxf(sqrtf(D[tid * NEXP + tid]), 1e-8f);
  __syncthreads();
  for (int e = tid; e < NN * NN; e += 256) {
    int n = e / NN, m = e - n * NN;
    float v = 0.f;
    if (n == m) v = 1.f;                              // self loop
    else if (m == NEXP) v = (n < NEXP) ? 1.f : 0.f;   // token -> each expert
    else if (n < NEXP && m < n) {                     // edge m->n for m<n
      float c = D[m * NEXP + n] / (nrm[m] * nrm[n]);
      v = (c > THR_EDGE) ? 1.f : 0.f;
    }
    Ar[n][m] = v;
  }
  __syncthreads();
  if (tid < NN) {
    float s = 0.f;
    for (int m = 0; m < NN; ++m) s += Ar[tid][m];
    dd[tid] = 1.0f / sqrtf(s);
  }
  __syncthreads();
  for (int e = tid; e < NN * NN; e += 256) {
    int n = e / NN, m = e - n * NN;
    float v = Ar[n][m] * dd[n] * dd[m];
    Al[n][m] = v;
    Ahat[e] = v;
  }
  __syncthreads();
  if (tid < NN) a0[tid] = Al[tid][NEXP];
  __syncthreads();
  if (tid < NN) {
    float s = 0.f;
    for (int m = 0; m < NN; ++m) s = fmaf(Al[tid][m], a0[m], s);
    q[tid] = s;
  }
}

// expW[m][d] = sum_k expT[m][k] * W0[k][d]
__global__ __launch_bounds__(256) void k_expW(const float* __restrict__ expT,
                                              const float* __restrict__ W0,
                                              float* __restrict__ expW) {
  int m = blockIdx.x, d = threadIdx.x;
  float acc = 0.f;
#pragma unroll 4
  for (int k = 0; k < DIM; ++k)
    acc = fmaf(expT[m * DIM + k], W0[k * DG + d], acc);
  expW[m * DG + d] = acc;
}

// CW1[n][d] = ((Ahat[:, :64] @ expW) @ W1)[n][d]
__global__ __launch_bounds__(256) void k_CW1(const float* __restrict__ Ahat,
                                             const float* __restrict__ expW,
                                             const float* __restrict__ W1,
                                             float* __restrict__ CW1) {
  __shared__ float c0[DG];
  int n = blockIdx.x, d = threadIdx.x;
  float acc = 0.f;
  for (int m = 0; m < NEXP; ++m)
    acc = fmaf(Ahat[n * NN + m], expW[m * DG + d], acc);
  c0[d] = acc;
  __syncthreads();
  float b = 0.f;
#pragma unroll 4
  for (int k = 0; k < DG; ++k)
    b = fmaf(c0[k], W1[k * DG + d], b);
  CW1[n * DG + d] = b;
}

// P[n][d] = (Ahat @ CW1)[n][d]
__global__ __launch_bounds__(256) void k_P(const float* __restrict__ Ahat,
                                           const float* __restrict__ CW1,
                                           float* __restrict__ P) {
  int n = blockIdx.x, d = threadIdx.x;
  float acc = 0.f;
  for (int m = 0; m < NN; ++m)
    acc = fmaf(Ahat[n * NN + m], CW1[m * DG + d], acc);
  P[n * DG + d] = acc;
}

// ---------------- k_mgemm v2: MFMA split-bf16 GEMM C = [relu](A@B) ----------------
template <int NT, bool RELU, bool OSPLIT>
__global__ __launch_bounds__(256) void k_mgemm(const ushort_t* __restrict__ Ah,
                                               const ushort_t* __restrict__ Al,
                                               const ushort_t* __restrict__ Bh,
                                               const ushort_t* __restrict__ Bl,
                                               float* __restrict__ C,
                                               ushort_t* __restrict__ Ch,
                                               ushort_t* __restrict__ Cl,
                                               int M, int N, int K) {
  int tid = threadIdx.x, lane = tid & 63, w = tid >> 6;
  int t0 = blockIdx.x * 64 + w * 16;
  int n0 = blockIdx.y * (NT * 16);
  int row = lane & 15, kg = lane >> 4;
  int KS = K >> 5;

  f32x4 acc[NT];
#pragma unroll
  for (int nt = 0; nt < NT; ++nt) acc[nt] = (f32x4){0.f, 0.f, 0.f, 0.f};

  const ushort_t* pA0 = Ah + (size_t)(t0 + row) * K + kg * 8;
  const ushort_t* pA1 = Al + (size_t)(t0 + row) * K + kg * 8;

  for (int kc = 0; kc < KS; kc += 8) {   // K-chunk of 256
    bf16x8 ah[8], al[8];
#pragma unroll
    for (int ks = 0; ks < 8; ++ks) {
      ah[ks] = *(const bf16x8*)(pA0 + (kc + ks) * 32);
      al[ks] = *(const bf16x8*)(pA1 + (kc + ks) * 32);
    }
#pragma unroll
    for (int nt = 0; nt < NT; ++nt) {
      int dt = (n0 >> 4) + nt;
      const ushort_t* pBh = Bh + ((size_t)dt * KS + kc) * 512 + lane * 8;
      const ushort_t* pBl = Bl + ((size_t)dt * KS + kc) * 512 + lane * 8;
      bf16x8 bh[8], bl[8];
#pragma unroll
      for (int ks = 0; ks < 8; ++ks) {
        bh[ks] = *(const bf16x8*)(pBh + ks * 512);
        bl[ks] = *(const bf16x8*)(pBl + ks * 512);
      }
#pragma unroll
      for (int ks = 0; ks < 8; ++ks) {
        acc[nt] = __builtin_amdgcn_mfma_f32_16x16x32_bf16(ah[ks], bh[ks], acc[nt], 0, 0, 0);
        acc[nt] = __builtin_amdgcn_mfma_f32_16x16x32_bf16(al[ks], bh[ks], acc[nt], 0, 0, 0);
        acc[nt] = __builtin_amdgcn_mfma_f32_16x16x32_bf16(ah[ks], bl[ks], acc[nt], 0, 0, 0);
        acc[nt] = __builtin_amdgcn_mfma_f32_16x16x32_bf16(al[ks], bl[ks], acc[nt], 0, 0, 0);
      }
    }
  }

#pragma unroll
  for (int nt = 0; nt < NT; ++nt) {
    int cc = n0 + nt * 16 + row;
#pragma unroll
    for (int r = 0; r < 4; ++r) {
      float v = acc[nt][r];
      if (RELU) v = fmaxf(v, 0.f);
      size_t o = (size_t)(t0 + kg * 4 + r) * N + cc;
      if (OSPLIT) {
        ushort_t h = f2bf(v);
        Ch[o] = h;
        Cl[o] = f2bf(v - bf2f(h));
      } else {
        C[o] = v;
      }
    }
  }
}

// ---------------- k_mix v2: G[nn][t][k] = sum_m Ahat[n0+nn][m]*relu(P[m][k]+q[m]V[t][k]) ----
__global__ __launch_bounds__(256) void k_mix(const float* __restrict__ V,
                                             const float* __restrict__ P,
                                             const float* __restrict__ Ahat,
                                             const float* __restrict__ q,
                                             ushort_t* __restrict__ Gh,
                                             ushort_t* __restrict__ Gl,
                                             int n0, int nch) {
  int t = blockIdx.x;
  int k = threadIdx.x;
  float v = V[(size_t)t * DG + k];
  float r[NN];
#pragma unroll
  for (int m = 0; m < NN; ++m)
    r[m] = fmaxf(fmaf(q[m], v, P[m * DG + k]), 0.f);
  for (int nn = 0; nn < nch; ++nn) {
    const float* arow = &Ahat[(size_t)(n0 + nn) * NN];  // uniform -> s_loads
    float a0 = 0.f, a1 = 0.f, a2 = 0.f, a3 = 0.f;
#pragma unroll
    for (int m = 0; m < 16; ++m) {
      a0 = fmaf(arow[m +  0], r[m +  0], a0);
      a1 = fmaf(arow[m + 16], r[m + 16], a1);
      a2 = fmaf(arow[m + 32], r[m + 32], a2);
      a3 = fmaf(arow[m + 48], r[m + 48], a3);
    }
    float acc = ((a0 + a1) + (a2 + a3)) + arow[64] * r[64];
    size_t idx = ((size_t)nn * T_TOK + t) * DG + k;
    ushort_t h = f2bf(acc);
    Gh[idx] = h;
    Gl[idx] = f2bf(acc - bf2f(h));
  }
}

// ---------------- k_zgemm v3 (MFMA split-bf16, dt-split for occupancy) ----------------
// Round-11 lesson: batching B-frags hurt (B is L1-hot; reg pressure was the cost).
// Root cause of the 83-98us: only 4.1 waves/SIMD of TOTAL work (Occupancy 17%).
// v3: grid gains a 4-wide dt-group axis -> 4x blocks, acc[16]->acc[4] (-48 regs),
// per-ks B loads (round-10 proven). Partials s2p[dtg][t][n]; k_final sums them.
__global__ __launch_bounds__(256, 4) void k_zgemm(const ushort_t* __restrict__ Gh,
                                                  const ushort_t* __restrict__ Gl,
                                                  const ushort_t* __restrict__ Wh,
                                                  const ushort_t* __restrict__ Wl,
                                                  const float* __restrict__ w3p,
                                                  float* __restrict__ s2p,
                                                  int n0) {
  int tid = threadIdx.x, lane = tid & 63, w = tid >> 6;
  int ny = blockIdx.y;
  int dtg = blockIdx.z;                   // dt-group: dt in [dtg*4, dtg*4+4)
  int t0 = blockIdx.x * 64 + w * 16;
  int row = lane & 15, kg = lane >> 4;

  const ushort_t* Ah = Gh + ((size_t)ny * T_TOK + t0 + row) * DG + kg * 8;
  const ushort_t* Al = Gl + ((size_t)ny * T_TOK + t0 + row) * DG + kg * 8;
  bf16x8 ah[8], al[8];
#pragma unroll
  for (int ks = 0; ks < 8; ++ks) {
    ah[ks] = *(const bf16x8*)(Ah + ks * 32);
    al[ks] = *(const bf16x8*)(Al + ks * 32);
  }

  f32x4 acc[4];
#pragma unroll
  for (int nt = 0; nt < 4; ++nt) acc[nt] = (f32x4){0.f, 0.f, 0.f, 0.f};

#pragma unroll
  for (int nt = 0; nt < 4; ++nt) {
    int dt = dtg * 4 + nt;
    const ushort_t* Bh = Wh + (size_t)dt * 4096 + lane * 8;
    const ushort_t* Bl = Wl + (size_t)dt * 4096 + lane * 8;
#pragma unroll
    for (int ks = 0; ks < 8; ++ks) {
      bf16x8 bh = *(const bf16x8*)(Bh + ks * 512);
      bf16x8 bl = *(const bf16x8*)(Bl + ks * 512);
      acc[nt] = __builtin_amdgcn_mfma_f32_16x16x32_bf16(ah[ks], bh, acc[nt], 0, 0, 0);
      acc[nt] = __builtin_amdgcn_mfma_f32_16x16x32_bf16(al[ks], bh, acc[nt], 0, 0, 0);
      acc[nt] = __builtin_amdgcn_mfma_f32_16x16x32_bf16(ah[ks], bl, acc[nt], 0, 0, 0);
      acc[nt] = __builtin_amdgcn_mfma_f32_16x16x32_bf16(al[ks], bl, acc[nt], 0, 0, 0);
    }
  }

  // epilogue: relu -> *w3p -> 16-lane reduce -> partial for this dt-group
  float v0 = 0.f, v1 = 0.f, v2 = 0.f, v3 = 0.f;
#pragma unroll
  for (int nt = 0; nt < 4; ++nt) {
    int dt = dtg * 4 + nt;
    float wpd = w3p[dt * 16 + row];
    v0 = fmaf(fmaxf(acc[nt][0], 0.f), wpd, v0);
    v1 = fmaf(fmaxf(acc[nt][1], 0.f), wpd, v1);
    v2 = fmaf(fmaxf(acc[nt][2], 0.f), wpd, v2);
    v3 = fmaf(fmaxf(acc[nt][3], 0.f), wpd, v3);
  }
#pragma unroll
  for (int off = 1; off < 16; off <<= 1) {
    v0 += __shfl_xor(v0, off, 64);
    v1 += __shfl_xor(v1, off, 64);
    v2 += __shfl_xor(v2, off, 64);
    v3 += __shfl_xor(v3, off, 64);
  }
  if (row == 0) {
    int t = t0 + kg * 4;
    int n = n0 + ny;
    size_t b = (size_t)dtg * T_TOK;
    s2p[(b + t + 0) * NN + n] = v0;
    s2p[(b + t + 1) * NN + n] = v1;
    s2p[(b + t + 2) * NN + n] = v2;
    s2p[(b + t + 3) * NN + n] = v3;
  }
}

// ---------------- final: sum dt-group partials, scores = Ahat[:64,:]@s2, softmax ----------------
__global__ __launch_bounds__(64) void k_final(const float* __restrict__ s2p,
                                              const float* __restrict__ Ahat,
                                              float* __restrict__ out) {
  __shared__ float s2l[NN];
  int t = blockIdx.x;
  int j = threadIdx.x;
  {
    float s = 0.f;
#pragma unroll
    for (int g = 0; g < 4; ++g)
      s += s2p[((size_t)g * T_TOK + t) * NN + j];
    s2l[j] = s;
    if (j == 0) {
      float s64 = 0.f;
#pragma unroll
      for (int g = 0; g < 4; ++g)
        s64 += s2p[((size_t)g * T_TOK + t) * NN + NEXP];
      s2l[NEXP] = s64;
    }
  }
  __syncthreads();
  float sc = 0.f;
  for (int m = 0; m < NN; ++m)
    sc = fmaf(Ahat[j * NN + m], s2l[m], sc);
  float mx = sc;
#pragma unroll
  for (int off = 32; off > 0; off >>= 1)
    mx = fmaxf(mx, __shfl_xor(mx, off, 64));
  float e = expf(sc - mx);
  float sum = e;
#pragma unroll
  for (int off = 32; off > 0; off >>= 1)
    sum += __shfl_xor(sum, off, 64);
  out[(size_t)t * NEXP + j] = e / sum;
}

// ---------------- launch ----------------
extern "C" void kernel_launch(void* const* d_in, const int* in_sizes, int n_in,
                              void* d_out, int out_size, void* d_ws, size_t ws_size,
                              hipStream_t stream) {
  (void)in_sizes; (void)n_in; (void)out_size; (void)ws_size;
  const float* x   = (const float*)d_in[0];
  const float* Xp  = (const float*)d_in[1];
  const float* mlp = (const float*)d_in[2];
  const float* W0  = (const float*)d_in[3];
  const float* W1  = (const float*)d_in[4];
  const float* W2  = (const float*)d_in[5];
  const float* W3  = (const float*)d_in[6];
  const float* pw  = (const float*)d_in[7];
  float* out = (float*)d_out;
  float* ws = (float*)d_ws;

  // workspace layout (floats), total 19,467,232 fl ~= 77.9 MB (< 82 MB proven)
  float* expT  = ws + 0;         // 65536
  float* expTT = ws + 65536;     // 65536 (dead after k_cos -> W2f overlay)
  float* w3p   = ws + 131072;    // 256
  float* D     = ws + 131328;    // 4096
  float* Ahat  = ws + 135424;    // 4240
  float* q     = ws + 139664;    // 80
  float* expW  = ws + 139744;    // 16384
  float* CW1   = ws + 156128;    // 16640
  float* P     = ws + 172768;    // 16640
  float* s2T   = ws + 189408;    // 133120 (unused now; kept for layout stability)
  float* V     = ws + 322528;    // 524288
  float* part  = ws + 846816;    // 524288 (expT K-split partials; dead early)
  ushort_t* W01f_h = (ushort_t*)(ws + 1371104);  // 131072 fl
  ushort_t* W01f_l = (ushort_t*)(ws + 1502176);  // 131072 fl
  // big arena at 1633248: split planes (dead before k_mix) overlaid by Gc
  float* arena = ws + 1633248;
  ushort_t* Xh    = (ushort_t*)(arena);                 // 1048576 fl
  ushort_t* Xl    = (ushort_t*)(arena + 1048576);       // 1048576 fl
  ushort_t* mlpf_h = (ushort_t*)(arena + 2097152);      // 524288 fl
  ushort_t* mlpf_l = (ushort_t*)(arena + 2621440);      // 524288 fl
  ushort_t* XTh   = (ushort_t*)(arena + 3145728);       // 1048576 fl
  ushort_t* XTl   = (ushort_t*)(arena + 4194304);       // 1048576 fl
  ushort_t* Gc_h  = (ushort_t*)(arena);                 // 8650752 fl (overlays splits)
  ushort_t* Gc_l  = (ushort_t*)(arena + 8650752);       // 8650752 fl
  float* s2p = ws + 18934752;                           // 4*2048*65 = 532480 fl
  ushort_t* W2f_h = (ushort_t*)(ws + 65536);            // 32768 fl (overlay expTT)
  ushort_t* W2f_l = (ushort_t*)(ws + 65536 + 32768);    // 32768 fl
  (void)s2T;

  // expert MLP (K-split, fp32 for the cos-threshold path)
  k_expT_ks<<<dim3(4, 16, 8), dim3(256), 0, stream>>>(Xp, mlp, part);
  k_expT_red<<<dim3(256), dim3(256), 0, stream>>>(part, expT, expTT);
  // independent setup
  k_W01<<<dim3(1024), dim3(256), 0, stream>>>(W0, W1, W01f_h, W01f_l);
  k_w3p<<<dim3(256), dim3(256), 0, stream>>>(W3, pw, w3p);
  k_splitX<<<dim3(1024), dim3(256), 0, stream>>>(x, Xh, Xl);
  k_splitB<<<dim3(128, 4), dim3(256), 0, stream>>>(mlp, mlpf_h, mlpf_l, DIM, DIM);
  // graph build
  k_cos<<<dim3(64), dim3(256), 0, stream>>>(expTT, D);
  k_splitW2<<<dim3(256), dim3(256), 0, stream>>>(W2, W2f_h, W2f_l);  // after k_cos
  k_buildA<<<dim3(1), dim3(256), 0, stream>>>(D, Ahat, q);
  k_expW<<<dim3(64), dim3(256), 0, stream>>>(expT, W0, expW);
  k_CW1<<<dim3(65), dim3(256), 0, stream>>>(Ahat, expW, W1, CW1);
  k_P<<<dim3(65), dim3(256), 0, stream>>>(Ahat, CW1, P);
  // XT = relu(x@mlp) as bf16 hi/lo (MFMA, NT=4 -> 512 blocks = 2/CU)
  k_mgemm<4, true, true><<<dim3(32, 16), dim3(256), 0, stream>>>(
      Xh, Xl, mlpf_h, mlpf_l, nullptr, XTh, XTl, T_TOK, DIM, DIM);
  // V = XT@W01 fp32 (MFMA, NT=2 -> 256 blocks)
  k_mgemm<2, false, false><<<dim3(32, 8), dim3(256), 0, stream>>>(
      XTh, XTl, W01f_h, W01f_l, V, nullptr, nullptr, T_TOK, DG, DIM);
  // chunked: G (bf16 hi/lo) = Ahat-mix; s2 partials = reduce(relu(G@W2)*w3p) via MFMA
  k_mix<<<dim3(T_TOK), dim3(256), 0, stream>>>(V, P, Ahat, q, Gc_h, Gc_l, 0, 33);
  k_zgemm<<<dim3(32, 33, 4), dim3(256), 0, stream>>>(Gc_h, Gc_l, W2f_h, W2f_l, w3p, s2p, 0);
  k_mix<<<dim3(T_TOK), dim3(256), 0, stream>>>(V, P, Ahat, q, Gc_h, Gc_l, 33, 32);
  k_zgemm<<<dim3(32, 32, 4), dim3(256), 0, stream>>>(Gc_h, Gc_l, W2f_h, W2f_l, w3p, s2p, 33);
  // scores + softmax -> out [2048,64]
  k_final<<<dim3(T_TOK), dim3(64), 0, stream>>>(s2p, Ahat, out);
}